// Round 2
// baseline (204.120 us; speedup 1.0000x reference)
//
#include <hip/hip_runtime.h>

// AttentionBlock: B=8, C=128, H=W=128, GROUPS=8, HEADS=8, HEAD_DIM=16
// R3: full affine collapse. GN+conv_in+attn+conv_out is affine in x per batch:
//   G = x x^T (Gram over spatial), m = x 1  -> stats (diag G, m), A = w_in*s,
//   S_h = A_h G A_h^T + u v^T + v u^T + N v v^T  (u = A m), W = softmax(S/4),
//   M = w_out (blkdiag(W) A), bias2 = w_out (blkdiag(W) v) + b_out,
//   out = x + M x + bias2.
// 3 kernels + 1 memset. x is read twice, written once. No h1 materialization.

#define NPOS 16384          // 128*128 spatial

typedef short short8 __attribute__((ext_vector_type(8)));   // 8 bf16
typedef float f32x4 __attribute__((ext_vector_type(4)));

__device__ __forceinline__ unsigned short f2bf(float f) {
    union { float f; unsigned u; } v; v.f = f;
    unsigned r = (v.u + 0x7fffu + ((v.u >> 16) & 1u)) >> 16;
    return (unsigned short)r;
}
__device__ __forceinline__ float bf2f(unsigned short u) {
    union { unsigned u; float f; } v; v.u = ((unsigned)u) << 16;
    return v.f;
}

// ---------------- K1: G[b] += Xslab Xslab^T ; m[b] += Xslab @ 1 ----------------
// grid 512 = 8 batches x 64 slabs of 256 spatial. LDS 64KB, granule-XOR swizzled.
__global__ __launch_bounds__(256, 2) void k_gram(const float* __restrict__ x,
                                                 float* __restrict__ G,
                                                 float* __restrict__ mv) {
    __shared__ unsigned short Xs[128 * 256];   // [c][d] bf16, granule-swizzled

    const int t = threadIdx.x;
    const int lane = t & 63, wv = t >> 6;
    const int q = lane >> 4, i16 = lane & 15;
    const int b = blockIdx.x >> 6;
    const int d0 = (blockIdx.x & 63) << 8;

    // stage x[b][c][d0..d0+255] -> bf16 LDS (coalesced float4 reads)
    const float* xb = x + (size_t)b * (128 * NPOS) + d0;
#pragma unroll
    for (int i = 0; i < 32; ++i) {
        int idx = t + i * 256;             // float4 index over 128x64
        int c = idx >> 6, d4 = idx & 63;
        float4 v = *((const float4*)(xb + (size_t)c * NPOS) + d4);
        ushort4 o;
        o.x = f2bf(v.x); o.y = f2bf(v.y); o.z = f2bf(v.z); o.w = f2bf(v.w);
        int g = d4 >> 1;                   // 8-ushort granule 0..31
        int sg = g ^ (c & 7);
        *(ushort4*)&Xs[c * 256 + (sg << 3) + ((d4 & 1) << 2)] = o;
    }
    __syncthreads();

    f32x4 acc[2][8];
    f32x4 macc[2];
#pragma unroll
    for (int a = 0; a < 2; ++a) {
        macc[a] = (f32x4){0.f, 0.f, 0.f, 0.f};
#pragma unroll
        for (int ct = 0; ct < 8; ++ct) acc[a][ct] = (f32x4){0.f, 0.f, 0.f, 0.f};
    }
    const short8 ones = {(short)0x3F80, (short)0x3F80, (short)0x3F80, (short)0x3F80,
                         (short)0x3F80, (short)0x3F80, (short)0x3F80, (short)0x3F80};
    const int r0 = wv * 32 + i16, r1 = r0 + 16;
#pragma unroll
    for (int ks = 0; ks < 8; ++ks) {
        int g = ks * 4 + q;
        short8 a0 = *(const short8*)&Xs[r0 * 256 + ((g ^ (r0 & 7)) << 3)];
        short8 a1 = *(const short8*)&Xs[r1 * 256 + ((g ^ (r1 & 7)) << 3)];
        macc[0] = __builtin_amdgcn_mfma_f32_16x16x32_bf16(a0, ones, macc[0], 0, 0, 0);
        macc[1] = __builtin_amdgcn_mfma_f32_16x16x32_bf16(a1, ones, macc[1], 0, 0, 0);
#pragma unroll
        for (int ct = 0; ct < 8; ++ct) {
            int rb = ct * 16 + i16;
            short8 bb = *(const short8*)&Xs[rb * 256 + ((g ^ (rb & 7)) << 3)];
            acc[0][ct] = __builtin_amdgcn_mfma_f32_16x16x32_bf16(a0, bb, acc[0][ct], 0, 0, 0);
            acc[1][ct] = __builtin_amdgcn_mfma_f32_16x16x32_bf16(a1, bb, acc[1][ct], 0, 0, 0);
        }
    }

    float* Gb = G + b * 16384;
#pragma unroll
    for (int a = 0; a < 2; ++a) {
        int rb = wv * 32 + a * 16 + q * 4;
#pragma unroll
        for (int ct = 0; ct < 8; ++ct)
#pragma unroll
            for (int r = 0; r < 4; ++r)
                atomicAdd(&Gb[(rb + r) * 128 + ct * 16 + i16], acc[a][ct][r]);
        if (i16 == 0) {
#pragma unroll
            for (int r = 0; r < 4; ++r)
                atomicAdd(&mv[b * 128 + rb + r], macc[a][r]);
        }
    }
}

// ---------------- K2: stats -> A,v,u -> T=A G -> S -> softmax -> T2 -> M, bias2
// grid 8 (one block = one batch = one CU), 512 threads (8 waves).
__global__ __launch_bounds__(512, 1) void k_fold(
    const float* __restrict__ G, const float* __restrict__ mv,
    const float* __restrict__ gn_w, const float* __restrict__ gn_b,
    const float* __restrict__ w_in, const float* __restrict__ b_in,
    const float* __restrict__ w_out, const float* __restrict__ b_out,
    unsigned short* __restrict__ Mb, float* __restrict__ bias2) {
    __shared__ unsigned short As[128 * 136];   // A bf16 (34.8 KB)
    __shared__ float T2f[128 * 132];           // 66 KB; low half aliased as Ts (G->T bf16)
    __shared__ float sW[8 * 16 * 16];          // softmax weights
    __shared__ float sm[128], ss[128], st[128], sv[128], su[128], t2v[128];
    __shared__ float red[8][128];              // v/u partial reduction

    unsigned short* Ts = (unsigned short*)T2f;

    const int t = threadIdx.x;
    const int lane = t & 63, wv = t >> 6;
    const int q = lane >> 4, i16 = lane & 15;
    const int b = blockIdx.x;
    const float* Gb = G + b * 16384;

    // ---- stats: mean from m, var from diag(G) ----
    if (t < 128) sm[t] = mv[b * 128 + t];
    __syncthreads();
    if (t < 128) {
        int g = t >> 4;
        float s1 = 0.f, s2 = 0.f;
#pragma unroll
        for (int k = 0; k < 16; ++k) {
            int c = g * 16 + k;
            s1 += sm[c];
            s2 += Gb[c * 128 + c];
        }
        const float invN = 1.0f / 262144.0f;
        float mean = s1 * invN;
        float var = s2 * invN - mean * mean;
        float rstd = rsqrtf(var + 1e-5f);
        float s = gn_w[t] * rstd;
        ss[t] = s;
        st[t] = gn_b[t] - mean * s;
    }
    __syncthreads();

    // ---- A = w_in*s (bf16 LDS), v = b_in + w_in@t, u = A@m (quarter-split) ----
    {
        int c = t & 127, quarter = t >> 7;
        float v = 0.f, u = 0.f;
        const float* wr = w_in + c * 128 + quarter * 32;
        unsigned short* ar = &As[c * 136 + quarter * 32];
#pragma unroll
        for (int k = 0; k < 32; ++k) {
            int kg = quarter * 32 + k;
            float w = wr[k];
            float a = w * ss[kg];
            ar[k] = f2bf(a);
            v += w * st[kg];
            u += a * sm[kg];
        }
        red[quarter][c] = v;
        red[4 + quarter][c] = u;
    }
    // stage G -> bf16 into Ts (all threads)
    for (int idx = t; idx < 16384; idx += 512)
        Ts[(idx >> 7) * 136 + (idx & 127)] = f2bf(Gb[idx]);
    __syncthreads();
    if (t < 128) {
        sv[t] = b_in[t] + red[0][t] + red[1][t] + red[2][t] + red[3][t];
        su[t] = red[4][t] + red[5][t] + red[6][t] + red[7][t];
    }
    __syncthreads();

    // ---- T = A @ G (MFMA, G symmetric so row-major Gs works as B) ----
    f32x4 tacc[8];
#pragma unroll
    for (int ct = 0; ct < 8; ++ct) tacc[ct] = (f32x4){0.f, 0.f, 0.f, 0.f};
    const int rA = wv * 16 + i16;
#pragma unroll
    for (int ks = 0; ks < 4; ++ks) {
        short8 af = *(const short8*)&As[rA * 136 + ks * 32 + q * 8];
#pragma unroll
        for (int ct = 0; ct < 8; ++ct) {
            short8 gb = *(const short8*)&Ts[(ct * 16 + i16) * 136 + ks * 32 + q * 8];
            tacc[ct] = __builtin_amdgcn_mfma_f32_16x16x32_bf16(af, gb, tacc[ct], 0, 0, 0);
        }
    }
    __syncthreads();
#pragma unroll
    for (int ct = 0; ct < 8; ++ct)
#pragma unroll
        for (int r = 0; r < 4; ++r)
            Ts[(wv * 16 + q * 4 + r) * 136 + ct * 16 + i16] = f2bf(tacc[ct][r]);
    __syncthreads();

    // ---- S_h = T_h A_h^T + rank-1 terms; softmax rows -> sW (wave wv = head) ----
    {
        f32x4 sacc = (f32x4){0.f, 0.f, 0.f, 0.f};
#pragma unroll
        for (int ks = 0; ks < 4; ++ks) {
            short8 tf = *(const short8*)&Ts[rA * 136 + ks * 32 + q * 8];
            short8 af = *(const short8*)&As[rA * 136 + ks * 32 + q * 8];
            sacc = __builtin_amdgcn_mfma_f32_16x16x32_bf16(tf, af, sacc, 0, 0, 0);
        }
        int J = wv * 16 + i16;
        float vJ = sv[J], uJ = su[J];
#pragma unroll
        for (int r = 0; r < 4; ++r) {
            int I = wv * 16 + q * 4 + r;
            float val = (sacc[r] + su[I] * vJ + sv[I] * uJ + 16384.f * sv[I] * vJ) * 0.25f;
            float mx = val;
#pragma unroll
            for (int msk = 1; msk < 16; msk <<= 1) mx = fmaxf(mx, __shfl_xor(mx, msk));
            float e = __expf(val - mx);
            float sum = e;
#pragma unroll
            for (int msk = 1; msk < 16; msk <<= 1) sum += __shfl_xor(sum, msk);
            sW[(wv * 16 + q * 4 + r) * 16 + i16] = e / sum;
        }
    }
    __syncthreads();   // also: all Ts reads done -> T2f may overwrite

    // ---- T2 = blkdiag(W) @ A  (f32, into T2f) ; t2v = blkdiag(W) @ v ----
    {
        int o = t & 127, quarter = t >> 7;
        int h = o >> 4, ii = o & 15;
        float a32[32];
#pragma unroll
        for (int kk = 0; kk < 32; ++kk) a32[kk] = 0.f;
#pragma unroll
        for (int j = 0; j < 16; ++j) {
            float wj = sW[(h * 16 + ii) * 16 + j];
            const ushort4* ar4 = (const ushort4*)&As[(h * 16 + j) * 136 + quarter * 32];
#pragma unroll
            for (int k4 = 0; k4 < 8; ++k4) {
                ushort4 vv = ar4[k4];
                a32[k4 * 4 + 0] += wj * bf2f(vv.x);
                a32[k4 * 4 + 1] += wj * bf2f(vv.y);
                a32[k4 * 4 + 2] += wj * bf2f(vv.z);
                a32[k4 * 4 + 3] += wj * bf2f(vv.w);
            }
        }
#pragma unroll
        for (int kk = 0; kk < 32; ++kk) T2f[o * 132 + quarter * 32 + kk] = a32[kk];
        if (t < 128) {
            float a = 0.f;
#pragma unroll
            for (int j = 0; j < 16; ++j) a += sW[(h * 16 + ii) * 16 + j] * sv[h * 16 + j];
            t2v[t] = a;
        }
    }
    __syncthreads();

    // ---- M = w_out @ T2 (f32 VALU) -> bf16 global ; bias2 = w_out @ t2v + b_out
    {
        int c = t & 127, quarter = t >> 7;
        float accM[32];
#pragma unroll
        for (int kk = 0; kk < 32; ++kk) accM[kk] = 0.f;
        const float* wor = w_out + c * 128;
        for (int o = 0; o < 128; ++o) {
            float w = wor[o];
            const float4* t2r = (const float4*)&T2f[o * 132 + quarter * 32];
#pragma unroll
            for (int k4 = 0; k4 < 8; ++k4) {
                float4 vv = t2r[k4];
                accM[k4 * 4 + 0] += w * vv.x;
                accM[k4 * 4 + 1] += w * vv.y;
                accM[k4 * 4 + 2] += w * vv.z;
                accM[k4 * 4 + 3] += w * vv.w;
            }
        }
        unsigned short* mrow = Mb + (size_t)b * 16384 + c * 128 + quarter * 32;
#pragma unroll
        for (int kk = 0; kk < 32; ++kk) mrow[kk] = f2bf(accM[kk]);
        if (t < 128) {
            float a = b_out[t];
            const float* wr = w_out + t * 128;
#pragma unroll
            for (int o = 0; o < 128; ++o) a += wr[o] * t2v[o];
            bias2[b * 128 + t] = a;
        }
    }
}

// ---------------- K3: out = x + M @ x + bias2 ----------------
// grid 1024 = 8 batches x 128 p-slabs of 128. LDS 32KB swizzled, M frags from global.
__global__ __launch_bounds__(256, 4) void k_out(const float* __restrict__ x,
                                                const unsigned short* __restrict__ Mb,
                                                const float* __restrict__ bias2,
                                                float* __restrict__ out) {
    __shared__ unsigned short Xt[128 * 128];   // [p][k] bf16, granule-swizzled
    __shared__ float b2s[128];

    const int t = threadIdx.x;
    const int lane = t & 63, wv = t >> 6;
    const int q = lane >> 4, i16 = lane & 15;
    const int b = blockIdx.x >> 7;
    const int p0 = (blockIdx.x & 127) << 7;

    if (t < 128) b2s[t] = bias2[b * 128 + t];

    // stage Xt[p][k] = bf16(x[k][p0+p])  (transpose, coalesced reads)
    const float* xb = x + (size_t)b * (128 * NPOS) + p0;
#pragma unroll
    for (int i = 0; i < 16; ++i) {
        int p = ((i & 1) << 6) + lane;
        int kq = (wv << 3) + (i >> 1);        // k-quad: k = kq*4..+3
        const float* col = xb + (size_t)(kq * 4) * NPOS + p;
        float a0 = col[0];
        float a1 = col[NPOS];
        float a2 = col[2 * NPOS];
        float a3 = col[3 * NPOS];
        ushort4 o; o.x = f2bf(a0); o.y = f2bf(a1); o.z = f2bf(a2); o.w = f2bf(a3);
        int g = kq >> 1;                      // granule 0..15
        int sg = g ^ (p & 7);
        *(ushort4*)&Xt[p * 128 + (sg << 3) + ((kq & 1) << 2)] = o;
    }
    __syncthreads();

    f32x4 acc[2][8];
#pragma unroll
    for (int a = 0; a < 2; ++a)
#pragma unroll
        for (int pt = 0; pt < 8; ++pt) acc[a][pt] = (f32x4){0.f, 0.f, 0.f, 0.f};

    const unsigned short* Mrow = Mb + (size_t)b * 16384;
#pragma unroll
    for (int ks = 0; ks < 4; ++ks) {
        short8 a0 = *(const short8*)&Mrow[(wv * 32 + i16) * 128 + ks * 32 + q * 8];
        short8 a1 = *(const short8*)&Mrow[(wv * 32 + 16 + i16) * 128 + ks * 32 + q * 8];
        int g = ks * 4 + q;
#pragma unroll
        for (int pt = 0; pt < 8; ++pt) {
            int pr = pt * 16 + i16;
            short8 bb = *(const short8*)&Xt[pr * 128 + ((g ^ (pr & 7)) << 3)];
            acc[0][pt] = __builtin_amdgcn_mfma_f32_16x16x32_bf16(a0, bb, acc[0][pt], 0, 0, 0);
            acc[1][pt] = __builtin_amdgcn_mfma_f32_16x16x32_bf16(a1, bb, acc[1][pt], 0, 0, 0);
        }
    }

    // epilogue: out = acc + bias2 + x  (x re-read f32, L2-hot from staging)
    float* ob = out + (size_t)b * (128 * NPOS) + p0;
#pragma unroll
    for (int a = 0; a < 2; ++a) {
        int cb = wv * 32 + a * 16 + q * 4;
#pragma unroll
        for (int pt = 0; pt < 8; ++pt) {
            int p = pt * 16 + i16;
#pragma unroll
            for (int r = 0; r < 4; ++r) {
                int c = cb + r;
                ob[(size_t)c * NPOS + p] = acc[a][pt][r] + b2s[c] + xb[(size_t)c * NPOS + p];
            }
        }
    }
}

extern "C" void kernel_launch(void* const* d_in, const int* in_sizes, int n_in,
                              void* d_out, int out_size, void* d_ws, size_t ws_size,
                              hipStream_t stream) {
    const float* x    = (const float*)d_in[0];
    const float* gn_w = (const float*)d_in[1];
    const float* gn_b = (const float*)d_in[2];
    const float* w_in = (const float*)d_in[3];
    const float* b_in = (const float*)d_in[4];
    const float* w_out= (const float*)d_in[5];
    const float* b_out= (const float*)d_in[6];
    float* out = (float*)d_out;

    // workspace layout (bytes):
    //   0      : G      524288  (8 x 128x128 f32, atomic-accumulated)
    //   524288 : mv     4096    (8 x 128 f32, atomic-accumulated)
    //   528384 : bias2  4096    (8 x 128 f32)
    //   532480 : Mb     262144  (8 x 128x128 bf16)
    char* ws = (char*)d_ws;
    float* G              = (float*)(ws + 0);
    float* mv             = (float*)(ws + 524288);
    float* bias2          = (float*)(ws + 528384);
    unsigned short* Mb    = (unsigned short*)(ws + 532480);

    hipMemsetAsync(d_ws, 0, 528384, stream);
    k_gram<<<dim3(512), dim3(256), 0, stream>>>(x, G, mv);
    k_fold<<<dim3(8), dim3(512), 0, stream>>>(G, mv, gn_w, gn_b, w_in, b_in,
                                              w_out, b_out, Mb, bias2);
    k_out<<<dim3(1024), dim3(256), 0, stream>>>(x, Mb, bias2, out);
}